// Round 4
// baseline (701.425 us; speedup 1.0000x reference)
//
#include <hip/hip_runtime.h>

namespace {
typedef unsigned short u16;
typedef __attribute__((ext_vector_type(8))) __bf16 bf16x8;
typedef __attribute__((ext_vector_type(4))) float f32x4;

constexpr long long kB  = 4096;
constexpr long long kOS = kB * 3600;

// ---- ws byte offsets ----
constexpr size_t oWkvT  = 0;                               // bf16 [768][512]
constexpr size_t oWqT   = oWkvT  + 768ull*512*2;           // bf16 [6][256][608]
constexpr size_t oWcomT = oWqT   + 6ull*256*608*2;         // bf16 [6][768][608]
constexpr size_t oWoutT = oWcomT + 6ull*768*608*2;         // bf16 [6][640][416]
constexpr size_t oLstmT = oWoutT + 6ull*640*416*2;         // bf16 [6][2432][1024]
constexpr size_t oBp    = oLstmT + 6ull*2432*1024*2;       // f32 [6][2432]
constexpr size_t oBkv   = oBp    + 6ull*2432*4;            // f32 [768]
constexpr size_t oZero  = oBkv   + 768*4;                  // 256 B
constexpr size_t oMask  = oZero  + 256;                    // f32 [4096][6]
constexpr size_t oArena = oMask  + 4096ull*6*4;
// phase-1 arena
constexpr size_t oHs2   = oArena;                          // bf16 [4096][3600]+64
constexpr size_t oRnn   = oHs2  + (4096ull*3600+64)*2;     // bf16 [4096][2400]
constexpr size_t oKV    = oRnn  + 4096ull*2400*2;          // bf16 [4096][768]
constexpr size_t oXbf   = oKV   + 4096ull*768*2;           // bf16 [4096][512]
constexpr size_t oQlay  = oXbf;                            // bf16 [4096][1536], overlays xbf AFTER kv gemm
// phase-2 overlay (phase-1 arena dead by then)
constexpr size_t oCqv   = oArena;                          // bf16 [4096][4608]  (kc|qc|vc per rim, 768 each)
constexpr size_t oCtx   = oCqv  + 4096ull*4608*2;          // bf16 [4096][2400]+64
}

__device__ __forceinline__ u16 f2b(float f) {
  union { float f; unsigned u; } x; x.f = f;
  unsigned r = (x.u + 0x7fffu + ((x.u >> 16) & 1u)) >> 16;
  return (u16)r;
}
__device__ __forceinline__ float b2f(u16 u) {
  union { unsigned u; float f; } x; x.u = ((unsigned)u) << 16;
  return x.f;
}
__device__ __forceinline__ float sigmoidf_(float x) { return 1.f / (1.f + __expf(-x)); }
__device__ __forceinline__ float tanhf_(float x) {
  // tanh(x) = 1 - 2/(exp(2x)+1); exp->inf => 1, exp->0 => -1 (saturation-safe)
  const float e = __expf(2.f * x);
  return 1.f - 2.f / (e + 1.f);
}

__device__ __forceinline__ void gload16(const void* g, void* l) {
  __builtin_amdgcn_global_load_lds((const __attribute__((address_space(1))) void*)g,
                                   (__attribute__((address_space(3))) void*)l, 16, 0, 0);
}
__device__ __forceinline__ void vmcnt0_barrier() {
  asm volatile("s_waitcnt vmcnt(0)" ::: "memory");
  __builtin_amdgcn_s_barrier();
}

union FragU { uint2 u2[2]; bf16x8 v; };

// ================= 128x128 bf16 MFMA GEMM, double-buffered pipelined =================
// BM=128, BN=128, BK=32. 256 threads = 4 waves (2x2), each wave 64x64 (acc 4x4 frags).
// Per K-step: ds_read cur frags -> issue global_load_lds of next tile -> MFMA ->
// s_waitcnt vmcnt(0) + raw s_barrier. One barrier/step; next-tile HBM latency hides
// under ds_read+MFMA (T3-minimum pipeline).
// MODE 0: C = A*B (+bias), store f32/bf16. MODE 1: final (+h_new, mask select, 2 outputs).
// MODE 2: gates (dual-source A: k<400 rnn, 400..999 hs2, else zero) + fused LSTM.
template<int MODE>
__global__ __launch_bounds__(256) void gemm128(
    const u16* __restrict__ A, int lda, int strideA,
    const u16* __restrict__ A2, int lda2, int strideA2,
    const u16* __restrict__ Bt, long strideB, int Kpad,
    void* __restrict__ C, int ldc, int strideC,
    const float* __restrict__ bias, int strideBias,
    int N, int nks, int storeBf16, int nx, int swz,
    const u16* __restrict__ zerobuf,
    const float* __restrict__ cs, const float* __restrict__ mask,
    float* __restrict__ c_upd, float* __restrict__ h_upd, u16* __restrict__ hnbf,
    const float* __restrict__ hs_in, float* __restrict__ out_state)
{
  __shared__ __align__(16) u16 As0[128 * 32];
  __shared__ __align__(16) u16 Bs0[128 * 32];
  __shared__ __align__(16) u16 As1[128 * 32];
  __shared__ __align__(16) u16 Bs1[128 * 32];

  // ---- block swizzle (m204 bijective XCD chunk) ----
  const int nwg = gridDim.x;
  const int orig = blockIdx.x;
  const int q = nwg >> 3, r = nwg & 7;
  const int xcd = orig & 7, bidx = orig >> 3;
  const int wgid = (xcd < r ? xcd * (q + 1) : r * (q + 1) + (xcd - r) * q) + bidx;
  int xt, mt, rim;
  if (swz == 0) {
    xt = wgid % nx;
    const int t2 = wgid / nx;
    mt = t2 & 31;
    rim = t2 >> 5;
  } else {
    const int g = wgid / 320;       // (rim, n-half) group; 320 = 32 m-tiles x 10 n-tiles
    const int rem = wgid % 320;
    rim = g >> 1;
    mt = rem / 10;
    xt = (g & 1) * 10 + rem % 10;
    if (xt >= 19) return;
  }
  const int m0 = mt * 128, n0 = xt * 128;

  A += (size_t)rim * strideA;
  if (MODE == 2) A2 += (size_t)rim * strideA2;
  Bt += (size_t)rim * strideB;
  if (bias) bias += (size_t)rim * strideBias;

  const int t = threadIdx.x;
  const int w = t >> 6, lane = t & 63;
  const int lrow = lane & 15, lk = lane >> 4;
  const int wr = w >> 1, wc = w & 1;

  f32x4 acc[4][4] = {};

  // chunk assignment: chunk c -> row c>>2, chunkcol (c&3)^((row>>1)&3). Each thread: c = t, t+256.
  const int rA0 = t >> 2,         cA0 = (t & 3) ^ ((rA0 >> 1) & 3);
  const int rA1 = (t + 256) >> 2, cA1 = (t & 3) ^ ((rA1 >> 1) & 3);

  auto stage = [&](int s, u16* Asd, u16* Bsd) {
    const int k0 = s * 32;
    const int gk0 = k0 + cA0 * 8, gk1 = k0 + cA1 * 8;
    const u16 *p0, *p1;
    if (MODE == 2) {
      p0 = (gk0 < 400)  ? A  + (size_t)(m0 + rA0) * lda  + gk0
         : (gk0 < 1000) ? A2 + (size_t)(m0 + rA0) * lda2 + (gk0 - 400)
                        : zerobuf;
      p1 = (gk1 < 400)  ? A  + (size_t)(m0 + rA1) * lda  + gk1
         : (gk1 < 1000) ? A2 + (size_t)(m0 + rA1) * lda2 + (gk1 - 400)
                        : zerobuf;
    } else {
      p0 = A + (size_t)(m0 + rA0) * lda + gk0;
      p1 = A + (size_t)(m0 + rA1) * lda + gk1;
    }
    gload16(p0, Asd + (size_t)t * 8);
    gload16(p1, Asd + (size_t)(t + 256) * 8);
    gload16(Bt + (size_t)(n0 + rA0) * Kpad + k0 + cA0 * 8, Bsd + (size_t)t * 8);
    gload16(Bt + (size_t)(n0 + rA1) * Kpad + k0 + cA1 * 8, Bsd + (size_t)(t + 256) * 8);
  };

  auto compute = [&](const u16* Asrc, const u16* Bsrc, int snext, u16* Asd, u16* Bsd, bool donext) {
    FragU af[4], bfr[4];
#pragma unroll
    for (int mf = 0; mf < 4; ++mf) {
      const int rr = wr * 64 + mf * 16 + lrow;
      const int sw = ((rr >> 1) & 3) << 4;
      const char* base = (const char*)Asrc + rr * 64;
      af[mf].u2[0] = *(const uint2*)(base + ((8 * lk) ^ sw));
      af[mf].u2[1] = *(const uint2*)(base + ((8 * lk + 32) ^ sw));
    }
#pragma unroll
    for (int nf = 0; nf < 4; ++nf) {
      const int rr = wc * 64 + nf * 16 + lrow;
      const int sw = ((rr >> 1) & 3) << 4;
      const char* base = (const char*)Bsrc + rr * 64;
      bfr[nf].u2[0] = *(const uint2*)(base + ((8 * lk) ^ sw));
      bfr[nf].u2[1] = *(const uint2*)(base + ((8 * lk + 32) ^ sw));
    }
    if (donext) stage(snext, Asd, Bsd);
#pragma unroll
    for (int mf = 0; mf < 4; ++mf)
#pragma unroll
      for (int nf = 0; nf < 4; ++nf)
        acc[mf][nf] = __builtin_amdgcn_mfma_f32_16x16x32_bf16(af[mf].v, bfr[nf].v, acc[mf][nf], 0, 0, 0);
    vmcnt0_barrier();
  };

  stage(0, As0, Bs0);
  vmcnt0_barrier();
  int s = 0;
  for (; s + 2 <= nks; s += 2) {
    compute(As0, Bs0, s + 1, As1, Bs1, s + 1 < nks);
    compute(As1, Bs1, s + 2, As0, Bs0, s + 2 < nks);
  }
  if (s < nks) compute(As0, Bs0, 0, As1, Bs1, false);

  if (MODE == 0) {
    float* Cf = (float*)C + (size_t)rim * strideC;
    u16*   Cu = (u16*)C + (size_t)rim * strideC;
#pragma unroll
    for (int mf = 0; mf < 4; ++mf)
#pragma unroll
      for (int r2 = 0; r2 < 4; ++r2) {
        const int m = m0 + wr * 64 + mf * 16 + 4 * lk + r2;
#pragma unroll
        for (int nf = 0; nf < 4; ++nf) {
          const int col = n0 + wc * 64 + nf * 16 + lrow;
          if (col < N) {
            float v = acc[mf][nf][r2];
            if (bias) v += bias[col];
            const size_t off = (size_t)m * ldc + col;
            if (storeBf16) Cu[off] = f2b(v); else Cf[off] = v;
          }
        }
      }
  } else if (MODE == 1) {
#pragma unroll
    for (int mf = 0; mf < 4; ++mf)
#pragma unroll
      for (int r2 = 0; r2 < 4; ++r2) {
        const int m = m0 + wr * 64 + mf * 16 + 4 * lk + r2;
        const float mk = mask[(size_t)m * 6 + rim];
#pragma unroll
        for (int nf = 0; nf < 4; ++nf) {
          const int col = n0 + wc * 64 + nf * 16 + lrow;
          if (col < 600) {
            const size_t off = (size_t)m * 3600 + rim * 600 + col;
            const float v = (mk != 0.f) ? (acc[mf][nf][r2] + h_upd[off]) : hs_in[off];
            h_upd[off] = v;
            out_state[off] = v;
          }
        }
      }
  } else {  // MODE 2: gates + fused LSTM. 64-col group = {i,f,g,o} x 16 units.
    const int nb = n0 + wc * 64;
    const int u = ((nb >> 6) << 4) + lrow;
    if (u < 600) {
      const float bi  = bias[nb + lrow];
      const float bff = bias[nb + 16 + lrow];
      const float bg  = bias[nb + 32 + lrow];
      const float bo  = bias[nb + 48 + lrow];
#pragma unroll
      for (int mf = 0; mf < 4; ++mf)
#pragma unroll
        for (int r2 = 0; r2 < 4; ++r2) {
          const int m = m0 + wr * 64 + mf * 16 + 4 * lk + r2;
          const float iv = acc[mf][0][r2] + bi;
          const float fv = acc[mf][1][r2] + bff;
          const float gv = acc[mf][2][r2] + bg;
          const float ov = acc[mf][3][r2] + bo;
          const size_t off = (size_t)m * 3600 + rim * 600 + u;
          const float cprev = cs[off];
          const float cv = sigmoidf_(fv) * cprev + sigmoidf_(iv) * tanhf_(gv);
          const float hv = sigmoidf_(ov) * tanhf_(cv);
          const float mk = mask[(size_t)m * 6 + rim];
          c_upd[off] = (mk != 0.f) ? cv : cprev;
          h_upd[off] = hv;
          hnbf[off]  = f2b(hv);
        }
    }
  }
}

// ================= weight pack: out[n][k] bf16 = in[k][colmap(n)] (LDS transpose) =========
__global__ __launch_bounds__(256) void pack_wt(
    const float* __restrict__ in1, long s1,
    const float* __restrict__ in2, long s2,
    int K1, int Ktot, int ldin, int Nreal,
    u16* __restrict__ out, long so, int Kpad, int gateperm)
{
  __shared__ float tile[64][65];
  const int rim = blockIdx.z;
  const float* i1 = in1 + (size_t)rim * s1;
  const float* i2 = in2 ? in2 + (size_t)rim * s2 : nullptr;
  u16* o = out + (size_t)rim * so;
  const int n0 = blockIdx.x * 64, k0 = blockIdx.y * 64;
  const int lane = threadIdx.x & 63, qq = threadIdx.x >> 6;
  const int n = n0 + lane;
  int col;
  if (gateperm) {
    const int g = (n >> 4) & 3, u = ((n >> 6) << 4) + (n & 15);
    col = (u < 600) ? g * 600 + u : -1;
  } else {
    col = (n < Nreal) ? n : -1;
  }
#pragma unroll
  for (int i = 0; i < 16; ++i) {
    const int kk = qq + 4 * i;
    const int k = k0 + kk;
    float v = 0.f;
    if (col >= 0) {
      if (k < K1) v = i1[(size_t)k * ldin + col];
      else if (k < Ktot) v = i2[(size_t)(k - K1) * ldin + col];
    }
    tile[kk][lane] = v;
  }
  __syncthreads();
#pragma unroll
  for (int i = 0; i < 16; ++i) {
    const int nn = qq + 4 * i;
    const int k = k0 + lane;
    if (k < Kpad) o[(size_t)(n0 + nn) * Kpad + k] = f2b(tile[lane][nn]);
  }
}

// combined [Wk | head-avg(Wv)] -> [768][512]
__global__ void pack_kvw(const float* __restrict__ Wk, const float* __restrict__ Wv,
                         u16* __restrict__ out) {
  const int i = blockIdx.x * 256 + threadIdx.x;
  if (i >= 768 * 512) return;
  const int n = i >> 9, k = i & 511;
  float v = 0.f;
  if (n < 256) v = Wk[(size_t)k * 256 + n];
  else if (n < 656) {
    const float* p = Wv + (size_t)k * 1600 + (n - 256);
    v = 0.25f * (p[0] + p[400] + p[800] + p[1200]);
  }
  out[i] = f2b(v);
}

// combined [Wkc | Wqc | Wvc] -> [6][768][608]
__global__ void pack_comw(const float* __restrict__ Wkc, const float* __restrict__ Wqc,
                          const float* __restrict__ Wvc, u16* __restrict__ out) {
  const long long i = (long long)blockIdx.x * 256 + threadIdx.x;
  if (i >= 6ll * 768 * 608) return;
  const int rim = (int)(i / (768 * 608));
  const int rem = (int)(i % (768 * 608));
  const int n = rem / 608, k = rem % 608;
  float v = 0.f;
  if (k < 600) {
    if (n < 128)      v = Wkc[(size_t)rim * 600 * 128 + (size_t)k * 128 + n];
    else if (n < 256) v = Wqc[(size_t)rim * 600 * 128 + (size_t)k * 128 + (n - 128)];
    else if (n < 656) v = Wvc[(size_t)rim * 600 * 400 + (size_t)k * 400 + (n - 256)];
  }
  out[i] = f2b(v);
}

__global__ void pack_misc(const float* __restrict__ lstm_b, const float* __restrict__ bk,
                          const float* __restrict__ bv,
                          float* __restrict__ bp, float* __restrict__ bkv, u16* __restrict__ zerobuf) {
  const int t = blockIdx.x * 256 + threadIdx.x;
  if (t < 6 * 2432) {
    const int rim = t / 2432, p = t % 2432;
    const int g = (p >> 4) & 3, u = ((p >> 6) << 4) + (p & 15);
    bp[t] = (u < 600) ? lstm_b[(size_t)rim * 2400 + g * 600 + u] : 0.f;
  }
  if (t < 768) {
    float v = 0.f;
    if (t < 256) v = bk[t];
    else if (t < 656) { const int j = t - 256; v = 0.25f * (bv[j] + bv[j + 400] + bv[j + 800] + bv[j + 1200]); }
    bkv[t] = v;
  }
  if (t < 128) zerobuf[t] = 0;
}

__global__ void pack_x(const float* __restrict__ inputs, u16* __restrict__ xbf) {
  const int idx = blockIdx.x * 256 + threadIdx.x;
  if (idx < 4096 * 512) {
    const int b = idx >> 9, c = idx & 511;
    xbf[idx] = f2b(inputs[(size_t)b * 518 + c]);
  }
}

__global__ void pack_hs2(const float* __restrict__ hs, u16* __restrict__ out) {
  const long long i8 = ((long long)blockIdx.x * 256 + threadIdx.x) * 8;
  const long long main_n = 4096ll * 3600;
  if (i8 + 8 <= main_n) {
    const float4 a = *reinterpret_cast<const float4*>(hs + i8);
    const float4 b = *reinterpret_cast<const float4*>(hs + i8 + 4);
    u16 r[8] = {f2b(a.x), f2b(a.y), f2b(a.z), f2b(a.w), f2b(b.x), f2b(b.y), f2b(b.z), f2b(b.w)};
    *reinterpret_cast<uint4*>(out + i8) = *reinterpret_cast<const uint4*>(r);
  } else if (i8 < main_n + 64) {
#pragma unroll
    for (int j = 0; j < 8; ++j) {
      const long long idx = i8 + j;
      if (idx < main_n + 64) out[idx] = f2b(idx < main_n ? hs[idx] : 0.f);
    }
  }
}

// ============ scores + softmax + top-k mask + rnn_in ============
__global__ __launch_bounds__(256) void score_kernel(
    const float* __restrict__ inputs, const u16* __restrict__ qlayb,
    const u16* __restrict__ kvb, const float* __restrict__ bk,
    const float* __restrict__ bkv,
    float* __restrict__ maskout, u16* __restrict__ rnnin)
{
  const int b = blockIdx.x;
  const int t = threadIdx.x;
  __shared__ float red[4][12];
  __shared__ float sprob[12];
  __shared__ float smask[6];

  const float k0v = b2f(kvb[(size_t)b * 768 + t]);
  const float bkv_ = bk[t];
  float part[12];
#pragma unroll
  for (int n = 0; n < 6; ++n) {
    const float q = b2f(qlayb[(size_t)b * 1536 + n * 256 + t]);
    part[2 * n]     = q * k0v;
    part[2 * n + 1] = q * bkv_;
  }
#pragma unroll
  for (int off = 32; off > 0; off >>= 1)
#pragma unroll
    for (int i = 0; i < 12; ++i)
      part[i] += __shfl_down(part[i], off);
  const int wave = t >> 6, lane = t & 63;
  if (lane == 0)
#pragma unroll
    for (int i = 0; i < 12; ++i) red[wave][i] = part[i];
  __syncthreads();
  if (t < 12) red[0][t] = (red[0][t] + red[1][t] + red[2][t] + red[3][t]) * (1.0f / 32.0f);
  __syncthreads();
  if (t < 6) {
    const float s0 = red[0][2 * t], s1 = red[0][2 * t + 1];
    const float mx = fmaxf(s0, s1);
    const float e0 = __expf(s0 - mx), e1 = __expf(s1 - mx);
    const float inv = 1.f / (e0 + e1);
    sprob[2 * t] = e0 * inv;
    sprob[2 * t + 1] = e1 * inv;
    const float* rd = inputs + (size_t)b * 518 + 512;
    const float mine = rd[t];
    int rank = 0;
#pragma unroll
    for (int j = 0; j < 6; ++j) {
      const float o = rd[j];
      rank += (o > mine) || (o == mine && j < t);
    }
    const float mk = (rank < 4) ? 1.f : 0.f;
    smask[t] = mk;
    maskout[(size_t)b * 6 + t] = mk;
  }
  __syncthreads();
  for (int base = t * 4; base < 2400; base += 1024) {
    const int n = base / 400, v = base % 400;
    const float p0 = sprob[2 * n], p1 = sprob[2 * n + 1], mk = smask[n];
    ushort4 st;
    st.x = f2b((p0 * b2f(kvb[(size_t)b * 768 + 256 + v + 0]) + p1 * bkv[256 + v + 0]) * mk);
    st.y = f2b((p0 * b2f(kvb[(size_t)b * 768 + 256 + v + 1]) + p1 * bkv[256 + v + 1]) * mk);
    st.z = f2b((p0 * b2f(kvb[(size_t)b * 768 + 256 + v + 2]) + p1 * bkv[256 + v + 2]) * mk);
    st.w = f2b((p0 * b2f(kvb[(size_t)b * 768 + 256 + v + 3]) + p1 * bkv[256 + v + 3]) * mk);
    *reinterpret_cast<ushort4*>(rnnin + (size_t)b * 2400 + base) = st;
  }
}

// ============ comm attention ============
__global__ __launch_bounds__(256) void comm_kernel(
    const u16* __restrict__ cqv, u16* __restrict__ ctx)
{
  const int b = blockIdx.x, t = threadIdx.x;
  __shared__ float skc[768], sqc[768], svc[2400];
  __shared__ float spc[4][6][6];
  for (int i = t * 4; i < 4608; i += 1024) {
    const ushort4 u4 = *reinterpret_cast<const ushort4*>(cqv + (size_t)b * 4608 + i);
    const u16 uu[4] = {u4.x, u4.y, u4.z, u4.w};
#pragma unroll
    for (int j = 0; j < 4; ++j) {
      const int ii = i + j;
      const int m = ii / 768, c = ii % 768;
      const float v = b2f(uu[j]);
      if (c < 128) skc[m * 128 + c] = v;
      else if (c < 256) sqc[m * 128 + (c - 128)] = v;
      else if (c < 656) svc[m * 400 + (c - 256)] = v;
    }
  }
  __syncthreads();
  if (t < 144) {
    const int h = t / 36, n = (t % 36) / 6, m = t % 6;
    float s = 0.f;
#pragma unroll
    for (int d = 0; d < 32; ++d) s += sqc[n * 128 + h * 32 + d] * skc[m * 128 + h * 32 + d];
    spc[h][n][m] = s * 0.17677669529663687f;
  }
  __syncthreads();
  if (t < 24) {
    const int h = t / 6, n = t % 6;
    float mx = -3.0e38f;
#pragma unroll
    for (int m = 0; m < 6; ++m) mx = fmaxf(mx, spc[h][n][m]);
    float e[6], sum = 0.f;
#pragma unroll
    for (int m = 0; m < 6; ++m) { e[m] = __expf(spc[h][n][m] - mx); sum += e[m]; }
    const float inv = 1.f / sum;
#pragma unroll
    for (int m = 0; m < 6; ++m) spc[h][n][m] = e[m] * inv;
  }
  __syncthreads();
  for (int base = t * 4; base < 2400; base += 1024) {
    const int n = base / 400, rr = base % 400, h = rr / 100, v = rr % 100;
    ushort4 st;
    float s0 = 0.f, s1 = 0.f, s2 = 0.f, s3 = 0.f;
#pragma unroll
    for (int m = 0; m < 6; ++m) {
      const float p = spc[h][n][m];
      const float* vm = &svc[m * 400 + h * 100 + v];
      s0 += p * vm[0]; s1 += p * vm[1]; s2 += p * vm[2]; s3 += p * vm[3];
    }
    st.x = f2b(s0); st.y = f2b(s1); st.z = f2b(s2); st.w = f2b(s3);
    *reinterpret_cast<ushort4*>(ctx + (size_t)b * 2400 + base) = st;
  }
}

// ================= launch =================
extern "C" void kernel_launch(void* const* d_in, const int* in_sizes, int n_in,
                              void* d_out, int out_size, void* d_ws, size_t ws_size,
                              hipStream_t stream) {
  const float* inputs = (const float*)d_in[0];
  const float* hs     = (const float*)d_in[1];
  const float* cs     = (const float*)d_in[2];
  const float* Wk     = (const float*)d_in[3];
  const float* bk     = (const float*)d_in[4];
  const float* Wv     = (const float*)d_in[5];
  const float* bv     = (const float*)d_in[6];
  const float* Wq     = (const float*)d_in[7];
  const float* lstm_k = (const float*)d_in[8];
  const float* lstm_r = (const float*)d_in[9];
  const float* lstm_b = (const float*)d_in[10];
  const float* Wkc    = (const float*)d_in[11];
  const float* Wvc    = (const float*)d_in[12];
  const float* Wqc    = (const float*)d_in[13];
  const float* Wout   = (const float*)d_in[14];

  float* out = (float*)d_out;
  float* out_state = out;
  float* h_upd = out + kOS;
  float* c_upd = out + 2 * kOS;
  u16*   hnbf  = (u16*)d_out;     // scratch alias in out_state slot (dead until final GEMM)

  char* wsb = (char*)d_ws;
  u16* WkvT  = (u16*)(wsb + oWkvT);
  u16* WqT   = (u16*)(wsb + oWqT);
  u16* WcomT = (u16*)(wsb + oWcomT);
  u16* WoutT = (u16*)(wsb + oWoutT);
  u16* LstmT = (u16*)(wsb + oLstmT);
  float* bp    = (float*)(wsb + oBp);
  float* bkv   = (float*)(wsb + oBkv);
  u16*   zerob = (u16*)(wsb + oZero);
  float* maskf = (float*)(wsb + oMask);
  u16* hs2   = (u16*)(wsb + oHs2);
  u16* rnn   = (u16*)(wsb + oRnn);
  u16* kvb   = (u16*)(wsb + oKV);
  u16* xbf   = (u16*)(wsb + oXbf);
  u16* qlayb = (u16*)(wsb + oQlay);
  u16* cqvb  = (u16*)(wsb + oCqv);
  u16* ctxb  = (u16*)(wsb + oCtx);

  dim3 B256(256);

  // ---- packs ----
  pack_misc<<<57, B256, 0, stream>>>(lstm_b, bk, bv, bp, bkv, zerob);
  pack_kvw<<<1536, B256, 0, stream>>>(Wk, Wv, WkvT);
  pack_comw<<<10944, B256, 0, stream>>>(Wkc, Wqc, Wvc, WcomT);
  pack_wt<<<dim3(4, 10, 6), B256, 0, stream>>>(Wq, 600ll*256, nullptr, 0, 600, 600, 256, 256, WqT, 256ll*608, 608, 0);
  pack_wt<<<dim3(10, 7, 6), B256, 0, stream>>>(Wout, 400ll*600, nullptr, 0, 400, 400, 600, 600, WoutT, 640ll*416, 416, 0);
  pack_wt<<<dim3(38, 16, 6), B256, 0, stream>>>(lstm_k, 400ll*2400, lstm_r, 600ll*2400, 400, 1000, 2400, 2400, LstmT, 2432ll*1024, 1024, 1);
  pack_x<<<8192, B256, 0, stream>>>(inputs, xbf);
  pack_hs2<<<7201, B256, 0, stream>>>(hs, hs2);

  // ---- kv = [x@Wk+bk | x@Wvavg+bvavg]  (N=656, K=512) ----
  gemm128<0><<<dim3(6*32), B256, 0, stream>>>(xbf, 512, 0, nullptr, 0, 0, WkvT, 0, 512,
      kvb, 768, 0, bkv, 0, 656, 16, 1, 6, 0, zerob,
      nullptr, nullptr, nullptr, nullptr, nullptr, nullptr, nullptr);
  // ---- qlay (N=256/rim, K=608) — overlays xbf, runs after kv ----
  gemm128<0><<<dim3(2*32*6), B256, 0, stream>>>(hs2, 3600, 600, nullptr, 0, 0, WqT, 256*608, 608,
      qlayb, 1536, 256, nullptr, 0, 256, 19, 1, 2, 0, zerob,
      nullptr, nullptr, nullptr, nullptr, nullptr, nullptr, nullptr);

  score_kernel<<<4096, B256, 0, stream>>>(inputs, qlayb, kvb, bk, bkv, maskf, rnn);

  // ---- gates (N=2432, K=1024) + fused LSTM; grouped XCD swizzle ----
  gemm128<2><<<dim3(3840), B256, 0, stream>>>(rnn, 2400, 400, hs2, 3600, 600, LstmT, 2432l*1024, 1024,
      nullptr, 0, 0, bp, 2432, 2432, 32, 0, 10, 1, zerob,
      cs, maskf, c_upd, h_upd, hnbf, nullptr, nullptr);

  // ---- comm projections fused: [kc|qc|vc] (N=656/rim, K=608) ----
  gemm128<0><<<dim3(6*32*6), B256, 0, stream>>>(hnbf, 3600, 600, nullptr, 0, 0, WcomT, 768l*608, 608,
      cqvb, 4608, 768, nullptr, 0, 656, 19, 1, 6, 0, zerob,
      nullptr, nullptr, nullptr, nullptr, nullptr, nullptr, nullptr);

  comm_kernel<<<4096, B256, 0, stream>>>(cqvb, ctxb);

  // ---- final: h_comm = ctx@Wout + h_new; masked select (N=640 pad, K=416) ----
  gemm128<1><<<dim3(5*32*6), B256, 0, stream>>>(ctxb, 2400, 400, nullptr, 0, 0, WoutT, 640l*416, 416,
      nullptr, 0, 0, nullptr, 0, 600, 13, 0, 5, 0, zerob,
      nullptr, maskf, nullptr, h_upd, nullptr, hs, out_state);
}